// Round 1
// baseline (848.247 us; speedup 1.0000x reference)
//
#include <hip/hip_runtime.h>
#include <math.h>

#define UNITS 1024
#define EMBD  256
#define BATCH 64
#define TLEN  128
#define VOCAB 32000
#define GIN_D (UNITS + EMBD)   // 1280

// ---------------- K1: c[b,j] = hidden[b,:] @ W2[:,j] + b1[j] + b2[j] ----------------
__global__ __launch_bounds__(256) void k_c(const float* __restrict__ hidden,
                                           const float* __restrict__ W2,
                                           const float* __restrict__ b1,
                                           const float* __restrict__ b2,
                                           float* __restrict__ c) {
    const int lane = threadIdx.x & 63;
    const int j = blockIdx.x * 64 + lane;
    const int b = blockIdx.y * 4 + (threadIdx.x >> 6);
    const float* hrow = hidden + (size_t)b * UNITS;
    const float* wcol = W2 + j;
    float acc = 0.f;
#pragma unroll 8
    for (int k = 0; k < UNITS; ++k)
        acc = fmaf(hrow[k], wcol[(size_t)k * UNITS], acc);
    c[(size_t)b * UNITS + j] = acc + b1[j] + b2[j];
}

// ---------------- K2: score[b,t] = sum_j tanh((enc@W1)[b,t,j] + c[b,j]) * V[j] ------
// 128x128 tile per block (full T rows of one batch b x 128 j-cols), K-chunk 16.
__global__ __launch_bounds__(256) void k_score(const float* __restrict__ enc,
                                               const float* __restrict__ W1,
                                               const float* __restrict__ c,
                                               const float* __restrict__ V,
                                               float* __restrict__ score) {
    __shared__ float As[16][132];   // [k][t]  (A transposed into LDS)
    __shared__ float Bs[16][132];   // [k][j]
    const int jt  = blockIdx.x;     // 0..7
    const int b   = blockIdx.y;     // 0..63
    const int tid = threadIdx.x;
    const int tx  = tid & 15;
    const int ty  = tid >> 4;

    const float* encb = enc + (size_t)b * TLEN * UNITS;

    float acc[8][8];
#pragma unroll
    for (int i = 0; i < 8; ++i)
#pragma unroll
        for (int j = 0; j < 8; ++j) acc[i][j] = 0.f;

    const int tA = tid >> 2;          // 0..63 (t row)
    const int kq = (tid & 3) * 4;     // 0,4,8,12
    const int jB = (tid & 31) * 4;    // 0..124
    const int kr = tid >> 5;          // 0..7

    for (int kc = 0; kc < UNITS; kc += 16) {
        const float4 a0 = *(const float4*)(encb + (size_t)tA * UNITS + kc + kq);
        const float4 a1 = *(const float4*)(encb + (size_t)(tA + 64) * UNITS + kc + kq);
        const float4 w0 = *(const float4*)(W1 + (size_t)(kc + kr) * UNITS + jt * 128 + jB);
        const float4 w1 = *(const float4*)(W1 + (size_t)(kc + kr + 8) * UNITS + jt * 128 + jB);
        __syncthreads();
        As[kq + 0][tA] = a0.x; As[kq + 1][tA] = a0.y;
        As[kq + 2][tA] = a0.z; As[kq + 3][tA] = a0.w;
        As[kq + 0][tA + 64] = a1.x; As[kq + 1][tA + 64] = a1.y;
        As[kq + 2][tA + 64] = a1.z; As[kq + 3][tA + 64] = a1.w;
        *(float4*)&Bs[kr][jB] = w0;
        *(float4*)&Bs[kr + 8][jB] = w1;
        __syncthreads();
#pragma unroll
        for (int k = 0; k < 16; ++k) {
            const float4 aA = *(const float4*)&As[k][ty * 4];
            const float4 aB = *(const float4*)&As[k][64 + ty * 4];
            const float4 bA = *(const float4*)&Bs[k][tx * 4];
            const float4 bB = *(const float4*)&Bs[k][64 + tx * 4];
            const float ar[8] = {aA.x, aA.y, aA.z, aA.w, aB.x, aB.y, aB.z, aB.w};
            const float br[8] = {bA.x, bA.y, bA.z, bA.w, bB.x, bB.y, bB.z, bB.w};
#pragma unroll
            for (int i = 0; i < 8; ++i)
#pragma unroll
                for (int j = 0; j < 8; ++j)
                    acc[i][j] = fmaf(ar[i], br[j], acc[i][j]);
        }
    }

    // epilogue: rs[row] = sum_cols tanh(acc + c[b,col]) * V[col]
    float rs[8] = {0.f, 0.f, 0.f, 0.f, 0.f, 0.f, 0.f, 0.f};
    const float* crow = c + (size_t)b * UNITS + jt * 128;
    const float* vrow = V + jt * 128;
#pragma unroll
    for (int j = 0; j < 8; ++j) {
        const int col = ((j & 4) << 4) + tx * 4 + (j & 3);
        const float cv = crow[col];
        const float vv = vrow[col];
#pragma unroll
        for (int i = 0; i < 8; ++i)
            rs[i] += tanhf(acc[i][j] + cv) * vv;
    }
#pragma unroll
    for (int off = 1; off < 16; off <<= 1)
#pragma unroll
        for (int i = 0; i < 8; ++i)
            rs[i] += __shfl_xor(rs[i], off);
    if (tx == 0) {
#pragma unroll
        for (int i = 0; i < 8; ++i) {
            const int row = ((i & 4) << 4) + ty * 4 + (i & 3);
            atomicAdd(&score[b * TLEN + row], rs[i]);
        }
    }
}

// ---------------- K3: softmax over t (bV is softmax-invariant -> skipped) -----------
__global__ void k_softmax(const float* __restrict__ score, float* __restrict__ attw) {
    const int b = blockIdx.x;
    const int lane = threadIdx.x;  // 0..63
    float s0 = score[b * TLEN + lane];
    float s1 = score[b * TLEN + 64 + lane];
    float m = fmaxf(s0, s1);
#pragma unroll
    for (int off = 1; off < 64; off <<= 1) m = fmaxf(m, __shfl_xor(m, off));
    const float e0 = expf(s0 - m);
    const float e1 = expf(s1 - m);
    float s = e0 + e1;
#pragma unroll
    for (int off = 1; off < 64; off <<= 1) s += __shfl_xor(s, off);
    const float inv = 1.f / s;
    attw[b * TLEN + lane] = e0 * inv;
    attw[b * TLEN + 64 + lane] = e1 * inv;
}

// ---------------- K4: context[b,k] = sum_t attw[b,t] * enc[b,t,k] -> gin[:, :1024] --
__global__ __launch_bounds__(256) void k_context(const float* __restrict__ enc,
                                                 const float* __restrict__ attw,
                                                 float* __restrict__ gin) {
    const int b = blockIdx.y;
    const int k = blockIdx.x * 256 + threadIdx.x;
    __shared__ float w[TLEN];
    if (threadIdx.x < TLEN) w[threadIdx.x] = attw[b * TLEN + threadIdx.x];
    __syncthreads();
    const float* e = enc + (size_t)b * TLEN * UNITS + k;
    float acc = 0.f;
#pragma unroll 8
    for (int t = 0; t < TLEN; ++t)
        acc = fmaf(w[t], e[(size_t)t * UNITS], acc);
    gin[(size_t)b * GIN_D + k] = acc;
}

// ---------------- K5: embedding gather -> gin[:, 1024:1280] -------------------------
__global__ void k_embed(const int* __restrict__ x, const float* __restrict__ emb,
                        float* __restrict__ gin) {
    const int b = blockIdx.x;
    const int e = threadIdx.x;  // 0..255
    const int row = x[b];
    gin[(size_t)b * GIN_D + UNITS + e] = emb[(size_t)row * EMBD + e];
}

// ---------------- K6: GRU gates + state. h0==0 => gates_h==0, r dead. ---------------
// state = (1-z)*hh, z=sigmoid(gin@K[:, i]+b), hh=tanh(gin@K[:, 2048+i]+b)
__global__ __launch_bounds__(256) void k_gru(const float* __restrict__ gin,
                                             const float* __restrict__ gru_k,
                                             const float* __restrict__ gru_b,
                                             float* __restrict__ state,
                                             float* __restrict__ stateT) {
    const int lane = threadIdx.x & 63;
    const int i = blockIdx.x * 64 + lane;
    const int b = blockIdx.y * 4 + (threadIdx.x >> 6);
    const float* g = gin + (size_t)b * GIN_D;
    const float* wz = gru_k + i;
    const float* wh = gru_k + 2048 + i;
    float az = 0.f, ah = 0.f;
#pragma unroll 4
    for (int k = 0; k < GIN_D; ++k) {
        const float gv = g[k];
        az = fmaf(gv, wz[(size_t)k * 3072], az);
        ah = fmaf(gv, wh[(size_t)k * 3072], ah);
    }
    az += gru_b[i];
    ah += gru_b[2048 + i];
    const float z = 1.f / (1.f + expf(-az));
    const float hh = tanhf(ah);
    const float st = (1.f - z) * hh;
    state[(size_t)b * UNITS + i] = st;
    stateT[(size_t)i * BATCH + b] = st;
}

// ---------------- K7: logits = state @ fc_W + fc_b ----------------------------------
// block: 64 cols x 4 waves (16 batches each); k-split 2 via atomics.
__global__ __launch_bounds__(256) void k_fc(const float* __restrict__ stateT,
                                            const float* __restrict__ fc_W,
                                            const float* __restrict__ fc_b,
                                            float* __restrict__ logits) {
    const int lane = threadIdx.x & 63;
    const int col = blockIdx.x * 64 + lane;
    const int b0 = __builtin_amdgcn_readfirstlane((int)(threadIdx.x >> 6) * 16);
    const int k0 = blockIdx.y * 512;
    float acc[16];
#pragma unroll
    for (int i = 0; i < 16; ++i) acc[i] = 0.f;
    const float* wp = fc_W + (size_t)k0 * VOCAB + col;
    const float* sp = stateT + (size_t)k0 * BATCH + b0;
#pragma unroll 2
    for (int k = 0; k < 512; ++k) {
        const float w = wp[(size_t)k * VOCAB];
        const float* s = sp + (size_t)k * BATCH;
        const float4 s0 = *(const float4*)(s);
        const float4 s1 = *(const float4*)(s + 4);
        const float4 s2 = *(const float4*)(s + 8);
        const float4 s3 = *(const float4*)(s + 12);
        acc[0]  = fmaf(s0.x, w, acc[0]);  acc[1]  = fmaf(s0.y, w, acc[1]);
        acc[2]  = fmaf(s0.z, w, acc[2]);  acc[3]  = fmaf(s0.w, w, acc[3]);
        acc[4]  = fmaf(s1.x, w, acc[4]);  acc[5]  = fmaf(s1.y, w, acc[5]);
        acc[6]  = fmaf(s1.z, w, acc[6]);  acc[7]  = fmaf(s1.w, w, acc[7]);
        acc[8]  = fmaf(s2.x, w, acc[8]);  acc[9]  = fmaf(s2.y, w, acc[9]);
        acc[10] = fmaf(s2.z, w, acc[10]); acc[11] = fmaf(s2.w, w, acc[11]);
        acc[12] = fmaf(s3.x, w, acc[12]); acc[13] = fmaf(s3.w == s3.w ? s3.y : s3.y, w, acc[13]);
        acc[14] = fmaf(s3.z, w, acc[14]); acc[15] = fmaf(s3.w, w, acc[15]);
    }
    if (blockIdx.y == 0) {
        const float fb = fc_b[col];
#pragma unroll
        for (int i = 0; i < 16; ++i) acc[i] += fb;
    }
#pragma unroll
    for (int i = 0; i < 16; ++i)
        atomicAdd(&logits[(size_t)(b0 + i) * VOCAB + col], acc[i]);
}

extern "C" void kernel_launch(void* const* d_in, const int* in_sizes, int n_in,
                              void* d_out, int out_size, void* d_ws, size_t ws_size,
                              hipStream_t stream) {
    const int*   x      = (const int*)  d_in[0];
    const float* hidden = (const float*)d_in[1];
    const float* enc    = (const float*)d_in[2];
    const float* emb    = (const float*)d_in[3];
    const float* W1     = (const float*)d_in[4];
    const float* b1     = (const float*)d_in[5];
    const float* W2     = (const float*)d_in[6];
    const float* b2     = (const float*)d_in[7];
    const float* V      = (const float*)d_in[8];
    // d_in[9] = bV: softmax-invariant, unused. d_in[11] = gru_rk: multiplies h0==0, unused.
    const float* gru_k  = (const float*)d_in[10];
    const float* gru_b  = (const float*)d_in[12];
    const float* fc_W   = (const float*)d_in[13];
    const float* fc_b   = (const float*)d_in[14];

    float* out       = (float*)d_out;
    float* logits    = out;                          // 64*32000
    float* state_out = out + (size_t)BATCH * VOCAB;  // 64*1024
    float* attw      = state_out + (size_t)BATCH * UNITS;  // 64*128

    float* c      = (float*)d_ws;        // 65536 f
    float* score  = c + 65536;           // 8192 f
    float* gin    = score + 8192;        // 81920 f
    float* stateT = gin + 81920;         // 65536 f  (total 884736 B)

    hipMemsetAsync(score, 0, (size_t)BATCH * TLEN * sizeof(float), stream);
    hipMemsetAsync(logits, 0, (size_t)BATCH * VOCAB * sizeof(float), stream);

    k_c      <<<dim3(16, 16), 256, 0, stream>>>(hidden, W2, b1, b2, c);
    k_score  <<<dim3(8, 64),  256, 0, stream>>>(enc, W1, c, V, score);
    k_softmax<<<64, 64, 0, stream>>>(score, attw);
    k_context<<<dim3(4, 64),  256, 0, stream>>>(enc, attw, gin);
    k_embed  <<<64, 256, 0, stream>>>(x, emb, gin);
    k_gru    <<<dim3(16, 16), 256, 0, stream>>>(gin, gru_k, gru_b, state_out, stateT);
    k_fc     <<<dim3(500, 2), 256, 0, stream>>>(stateT, fc_W, fc_b, logits);
}